// Round 15
// baseline (177.016 us; speedup 1.0000x reference)
//
#include <hip/hip_runtime.h>
#include <math.h>

#define HIDDEN 64
#define SEQ 128
#define BATCH 64
#define NPTS (BATCH * SEQ)   // 8192
#define TMAXV 20.0f
#define L2E 1.4426950408889634f
#define LN2 0.6931471805599453f

typedef float v2f __attribute__((ext_vector_type(2)));

__device__ __forceinline__ float fexp2(float x) { return __builtin_amdgcn_exp2f(x); }
__device__ __forceinline__ float flog2(float x) { return __builtin_amdgcn_logf(x); }
__device__ __forceinline__ float frcp(float x)  { return __builtin_amdgcn_rcpf(x); }
__device__ __forceinline__ float fsigmoid(float x) { return frcp(1.0f + fexp2(-x * L2E)); }
__device__ __forceinline__ float ftanh(float x)    { return 1.0f - 2.0f * frcp(1.0f + fexp2(2.0f * x * L2E)); }

// Raw barrier: orders LDS only (lgkmcnt), does NOT drain vmcnt.
__device__ __forceinline__ void barrier_lds_only() {
    asm volatile("s_waitcnt lgkmcnt(0)" ::: "memory");
    __builtin_amdgcn_s_barrier();
}

// ---- DPP wave64 sum: VALU-pipe cross-lane (no LDS round trips). Result uniform.
template <int CTRL>
__device__ __forceinline__ float dpp_mov(float x) {
    int r = __builtin_amdgcn_update_dpp(0, __float_as_int(x), CTRL, 0xf, 0xf, false);
    return __int_as_float(r);
}
__device__ __forceinline__ float wave_sum_dpp(float x) {
    x += dpp_mov<0x111>(x);   // row_shr:1
    x += dpp_mov<0x112>(x);   // row_shr:2
    x += dpp_mov<0x114>(x);   // row_shr:4
    x += dpp_mov<0x118>(x);   // row_shr:8  -> lane 16r+15 = row sum
    x += dpp_mov<0x142>(x);   // row_bcast:15
    x += dpp_mov<0x143>(x);   // row_bcast:31 -> lane 63 = total
    return __int_as_float(__builtin_amdgcn_readlane(__float_as_int(x), 63));
}

__device__ __forceinline__ float wave_sum_shfl(float v) {
    v += __shfl_xor(v, 1);  v += __shfl_xor(v, 2);  v += __shfl_xor(v, 4);
    v += __shfl_xor(v, 8);  v += __shfl_xor(v, 16); v += __shfl_xor(v, 32);
    return v;
}

// Stash 4 floats into AGPRs ("=a": compiler-allocated accumulator registers).
// Volatile is fine HERE (runs once, prologue).
#define AW4(d0, d1, d2, d3, q)                                          \
    asm volatile("v_accvgpr_write_b32 %0, %4\n\t"                       \
                 "v_accvgpr_write_b32 %1, %5\n\t"                       \
                 "v_accvgpr_write_b32 %2, %6\n\t"                       \
                 "v_accvgpr_write_b32 %3, %7"                           \
                 : "=a"(d0), "=a"(d1), "=a"(d2), "=a"(d3)               \
                 : "v"((q).x), "v"((q).y), "v"((q).z), "v"((q).w))

// Single AGPR->VGPR read. NON-volatile: the scheduler may interleave it freely
// with FMAs/ds_reads (r14's volatile 8-read blocks serialized the whole dot,
// +400 cy). The dummy loop-variant operand %2 pins it inside the loop so LICM
// cannot hoist 64 reads into 64 live VGPRs (r11's spill failure mode); remat,
// if any, costs ~2 cy instead of a memory access.
__device__ __forceinline__ float agpr_get(float a, int dep) {
    float u;
    asm("v_accvgpr_read_b32 %0, %1" : "=v"(u) : "a"(a), "v"(dep));
    return u;
}

// Blocks [0,64): LSTM rollout, one batch per block, 256 threads (thread j = gate-row j).
// r3 structure (67.7us) + AGPR-resident weights with SCHEDULABLE reads.
// Revised model from r14: r3 = ~950 cy serial chain + ~300 cy exposed weight
// latency. This kernel deletes the weight-latency term (zero in-loop vmem)
// without r14's serialization penalty.
// Blocks [64,192): expert-expert MMD term (r13-identical).
__global__ __launch_bounds__(256, 1) void gen_and_ee(
    const float* __restrict__ upool,   // [B,S]
    const float* __restrict__ texp,    // [B,S]
    const float* __restrict__ Wih,     // [256]
    const float* __restrict__ Whh,     // [256,64]
    const float* __restrict__ bih,     // [256]
    const float* __restrict__ bhh,     // [256]
    const float* __restrict__ Vw,      // [64]
    const float* __restrict__ Vb,      // [1]
    float* __restrict__ tl,            // [NPTS] workspace
    float* __restrict__ out)           // [1] loss accumulator
{
    // [0,4096)      qbuf float2[2048] (EE) / act_s[2][256] = floats [0,512) (LSTM)
    // [4096,4352)   hx_s[4][64]
    // [4352,4480)   lu_s[128]
    // [4480,4544)   pad (build canary: LDS 18176 B, distinct from r14's 18432)
    __shared__ __align__(16) float smem[4544];

    const int bid = blockIdx.x;
    const int tid = threadIdx.x;

    if (bid < BATCH) {
        const int h  = tid & 63;
        const int wv = tid >> 6;

        float* act  = smem;                     // [2][256]
        float* hx_s = smem + 4096 + wv * 64;    // this wave's replica
        float* lu_s = smem + 4352;

        // ---- W_hh row `tid` -> 64 AGPR-resident floats (A{j} = W[tid][j]) ----
        float A0,A1,A2,A3,A4,A5,A6,A7,A8,A9,A10,A11,A12,A13,A14,A15;
        float A16,A17,A18,A19,A20,A21,A22,A23,A24,A25,A26,A27,A28,A29,A30,A31;
        float A32,A33,A34,A35,A36,A37,A38,A39,A40,A41,A42,A43,A44,A45,A46,A47;
        float A48,A49,A50,A51,A52,A53,A54,A55,A56,A57,A58,A59,A60,A61,A62,A63;
        {
            const float4* wrow = (const float4*)(Whh + tid * 64);
            float4 q;
            q = wrow[0];  AW4(A0,  A1,  A2,  A3,  q);
            q = wrow[1];  AW4(A4,  A5,  A6,  A7,  q);
            q = wrow[2];  AW4(A8,  A9,  A10, A11, q);
            q = wrow[3];  AW4(A12, A13, A14, A15, q);
            q = wrow[4];  AW4(A16, A17, A18, A19, q);
            q = wrow[5];  AW4(A20, A21, A22, A23, q);
            q = wrow[6];  AW4(A24, A25, A26, A27, q);
            q = wrow[7];  AW4(A28, A29, A30, A31, q);
            q = wrow[8];  AW4(A32, A33, A34, A35, q);
            q = wrow[9];  AW4(A36, A37, A38, A39, q);
            q = wrow[10]; AW4(A40, A41, A42, A43, q);
            q = wrow[11]; AW4(A44, A45, A46, A47, q);
            q = wrow[12]; AW4(A48, A49, A50, A51, q);
            q = wrow[13]; AW4(A52, A53, A54, A55, q);
            q = wrow[14]; AW4(A56, A57, A58, A59, q);
            q = wrow[15]; AW4(A60, A61, A62, A63, q);
        }

        const float bias = bih[tid] + bhh[tid];
        const float wih  = Wih[tid];
        const float vw   = Vw[h];      // all waves: redundant sigma reduction
        const float vb   = Vb[0];

        if (tid < SEQ) lu_s[tid] = -flog2(upool[bid * SEQ + tid]) * LN2;
        hx_s[h] = 0.0f;                // every wave zeroes its own replica
        float cx = 0.0f;
        barrier_lds_only();

        // step 0: hx = 0 -> sigma = elu(Vb)+1 (uniform)
        float sg0 = (vb > 0.0f) ? (vb + 1.0f) : fexp2(vb * L2E);
        float cum = lu_s[0] * frcp(sg0);
        float keep = (tid == 0) ? cum : 0.0f;   // thread t keeps cum of step t

        // Per k-pair kk: weights A[8kk..8kk+7]; FMA pairing/order identical to
        // r3's w2[] (bit-exact). Reads are independent schedulable 2-cy ops.
#define GATE_KK(kk, B0, B1, B2, B3, B4, B5, B6, B7)                     \
        {                                                               \
            float4 va  = h4[2 * (kk)];                                  \
            float4 vbq = h4[2 * (kk) + 1];                              \
            a0 = a0 + (v2f){agpr_get(B0, s), agpr_get(B1, s)} * (v2f){va.x, va.y};   \
            a1 = a1 + (v2f){agpr_get(B2, s), agpr_get(B3, s)} * (v2f){va.z, va.w};   \
            a2 = a2 + (v2f){agpr_get(B4, s), agpr_get(B5, s)} * (v2f){vbq.x, vbq.y}; \
            a3 = a3 + (v2f){agpr_get(B6, s), agpr_get(B7, s)} * (v2f){vbq.z, vbq.w}; \
        }

        #pragma unroll 1
        for (int s = 0; s < SEQ - 1; ++s) {
            const float4* h4 = (const float4*)(smem + 4096 + wv * 64);
            v2f a0 = {0.f, 0.f}, a1 = {0.f, 0.f}, a2 = {0.f, 0.f}, a3 = {0.f, 0.f};
            GATE_KK(0, A0,  A1,  A2,  A3,  A4,  A5,  A6,  A7)
            GATE_KK(1, A8,  A9,  A10, A11, A12, A13, A14, A15)
            GATE_KK(2, A16, A17, A18, A19, A20, A21, A22, A23)
            GATE_KK(3, A24, A25, A26, A27, A28, A29, A30, A31)
            GATE_KK(4, A32, A33, A34, A35, A36, A37, A38, A39)
            GATE_KK(5, A40, A41, A42, A43, A44, A45, A46, A47)
            GATE_KK(6, A48, A49, A50, A51, A52, A53, A54, A55)
            GATE_KK(7, A56, A57, A58, A59, A60, A61, A62, A63)

            v2f aa = (a0 + a1) + (a2 + a3);
            float g = (aa.x + aa.y) + bias + cum * wih;
            float a = (wv == 2) ? ftanh(g) : fsigmoid(g);
            act[(s & 1) * 256 + tid] = a;
            barrier_lds_only();        // the ONLY barrier per step; no vmcnt drain

            // redundant cell update in every wave (bit-identical across waves)
            float ig = act[(s & 1) * 256 + h];
            float fg = act[(s & 1) * 256 + 64 + h];
            float gg = act[(s & 1) * 256 + 128 + h];
            float og = act[(s & 1) * 256 + 192 + h];
            cx = fg * cx + ig * gg;
            float hx = og * ftanh(cx);
            hx_s[h] = hx;              // own replica; in-wave lgkmcnt ordering only

            float tot = wave_sum_dpp(hx * vw);
            float xx  = tot + vb;
            float sg  = (xx > 0.0f) ? (xx + 1.0f) : fexp2(xx * L2E);
            cum += lu_s[s + 1] * frcp(sg);

            keep = (tid == s + 1) ? cum : keep;   // threads 128..255 never match
        }
#undef GATE_KK
        if (tid < SEQ) tl[bid * SEQ + tid] = keep;
    } else {
        // ---------------- expert-expert MMD term (r13-identical) ----------------
        const int eb = bid - BATCH;      // 0..127
        const int pc = eb & 31;          // p-chunk (256 points)
        const int qs = eb >> 5;          // q-split (2048 points)

        float2* qbuf = (float2*)smem;    // [2048]

        const int p = pc * 256 + tid;
        const float tp = texp[p];
        const float mp = (tp < TMAXV && tp > 0.0f) ? 1.0f : 0.0f;

        const int q0 = qs * 2048;
        for (int i = tid; i < 2048; i += 256) {
            float tq = texp[q0 + i];
            float mq = (tq < TMAXV && tq > 0.0f) ? 1.0f : 0.0f;
            qbuf[i] = make_float2(tq, mq);
        }
        __syncthreads();

        float acc = 0.0f;
        #pragma unroll 4
        for (int i = 0; i < 2048; ++i) {
            float2 qq = qbuf[i];
            float d = tp - qq.x;
            acc = fmaf(qq.y, fexp2(d * d * (-L2E)), acc);
        }
        acc *= mp;
        acc = wave_sum_shfl(acc);
        if ((tid & 63) == 0) atomicAdd(out, acc);
    }
}

// ll + le terms. Grid (32, 16): 32 p-chunks of 256 x 16 q-splits of 512.
__global__ __launch_bounds__(256) void ll_le(
    const float* __restrict__ texp,
    const float* __restrict__ tl,
    float* __restrict__ out)
{
    __shared__ __align__(16) float4 qbuf[512];
    __shared__ float red[4];

    const int pc = blockIdx.x;
    const int qs = blockIdx.y;
    const int tid = threadIdx.x;

    const int p = pc * 256 + tid;
    const float tlp = tl[p];
    const float mlp = (tlp < TMAXV && tlp > 0.0f) ? 1.0f : 0.0f;

    const int q0 = qs * 512;
    for (int i = tid; i < 512; i += 256) {
        float tq = tl[q0 + i];
        float mq = (tq < TMAXV && tq > 0.0f) ? 1.0f : 0.0f;
        float te = texp[q0 + i];
        float me = (te < TMAXV && te > 0.0f) ? 1.0f : 0.0f;
        qbuf[i] = make_float4(tq, mq, te, me);
    }
    __syncthreads();

    float val = 0.0f;
    // learner times are cumsum of Exp(1) increments: most p-points exceed T_MAX;
    // fully-masked waves skip the whole q-loop (wave-uniform branch).
    if (__ballot(mlp != 0.0f) != 0ULL) {
        float a_ll = 0.0f, a_le = 0.0f;
        #pragma unroll 4
        for (int i = 0; i < 512; ++i) {
            float4 q = qbuf[i];
            float d1 = tlp - q.x;
            a_ll = fmaf(q.y, fexp2(d1 * d1 * (-L2E)), a_ll);
            float d2 = tlp - q.z;
            a_le = fmaf(q.w, fexp2(d2 * d2 * (-L2E)), a_le);
        }
        val = mlp * (a_ll - 2.0f * a_le);
    }

    val = wave_sum_shfl(val);
    if ((tid & 63) == 0) red[tid >> 6] = val;
    __syncthreads();
    if (tid == 0) atomicAdd(out, red[0] + red[1] + red[2] + red[3]);
}

extern "C" void kernel_launch(void* const* d_in, const int* in_sizes, int n_in,
                              void* d_out, int out_size, void* d_ws, size_t ws_size,
                              hipStream_t stream) {
    const float* upool = (const float*)d_in[0];
    const float* texp  = (const float*)d_in[1];
    const float* Wih   = (const float*)d_in[2];
    const float* Whh   = (const float*)d_in[3];
    const float* bih   = (const float*)d_in[4];
    const float* bhh   = (const float*)d_in[5];
    const float* Vw    = (const float*)d_in[6];
    const float* Vb    = (const float*)d_in[7];
    float* out = (float*)d_out;
    float* tl  = (float*)d_ws;   // 8192 floats = 32 KB

    hipMemsetAsync(out, 0, sizeof(float), stream);
    hipLaunchKernelGGL(gen_and_ee, dim3(BATCH + 128), dim3(256), 0, stream,
                       upool, texp, Wih, Whh, bih, bhh, Vw, Vb, tl, out);
    hipLaunchKernelGGL(ll_le, dim3(32, 16), dim3(256), 0, stream, texp, tl, out);
}

// Round 16
// 154.564 us; speedup vs baseline: 1.1453x; 1.1453x over previous
//
#include <hip/hip_runtime.h>
#include <math.h>

#define HIDDEN 64
#define SEQ 128
#define BATCH 64
#define NPTS (BATCH * SEQ)   // 8192
#define TMAXV 20.0f
#define L2E 1.4426950408889634f
#define LN2 0.6931471805599453f

typedef float v2f __attribute__((ext_vector_type(2)));

__device__ __forceinline__ float fexp2(float x) { return __builtin_amdgcn_exp2f(x); }
__device__ __forceinline__ float flog2(float x) { return __builtin_amdgcn_logf(x); }
__device__ __forceinline__ float frcp(float x)  { return __builtin_amdgcn_rcpf(x); }
__device__ __forceinline__ float fsigmoid(float x) { return frcp(1.0f + fexp2(-x * L2E)); }
__device__ __forceinline__ float ftanh(float x)    { return 1.0f - 2.0f * frcp(1.0f + fexp2(2.0f * x * L2E)); }

// Raw barrier: orders LDS only (lgkmcnt), does NOT drain vmcnt.
__device__ __forceinline__ void barrier_lds_only() {
    asm volatile("s_waitcnt lgkmcnt(0)" ::: "memory");
    __builtin_amdgcn_s_barrier();
}

// ---- DPP helpers (VALU pipe, no LDS) ----
template <int CTRL>
__device__ __forceinline__ float dpp_mov(float x) {
    int r = __builtin_amdgcn_update_dpp(0, __float_as_int(x), CTRL, 0xf, 0xf, false);
    return __int_as_float(r);
}
__device__ __forceinline__ float wave_sum_dpp(float x) {
    x += dpp_mov<0x111>(x);   // row_shr:1
    x += dpp_mov<0x112>(x);   // row_shr:2
    x += dpp_mov<0x114>(x);   // row_shr:4
    x += dpp_mov<0x118>(x);   // row_shr:8  -> lane 16r+15 = row sum
    x += dpp_mov<0x142>(x);   // row_bcast:15
    x += dpp_mov<0x143>(x);   // row_bcast:31 -> lane 63 = total
    return __int_as_float(__builtin_amdgcn_readlane(__float_as_int(x), 63));
}

__device__ __forceinline__ float wave_sum_shfl(float v) {
    v += __shfl_xor(v, 1);  v += __shfl_xor(v, 2);  v += __shfl_xor(v, 4);
    v += __shfl_xor(v, 8);  v += __shfl_xor(v, 16); v += __shfl_xor(v, 32);
    return v;
}

// Blocks [0,64): LSTM rollout, one batch per block, 256 threads.
// QUAD-GATE MAPPING: thread (wave w, lane l) owns gate row (l&3)*64 + 16w + (l>>2),
// so lanes 4j..4j+3 of a wave hold gates i,f,g,o of hidden unit u=16w+j.
//   - gate exchange: 4 quad_perm DPP movs (~35 cy) instead of r3's LDS
//     store + barrier + 4 LDS reads (~300 cy). Cell update redundant in-quad.
//   - per step, only the 64 new hx cross waves (16/wave, conflict-free
//     stores) across ONE barrier; sigma is computed at the TOP of the next
//     iteration from hx_s[l] with r3's exact lane mapping + DPP association
//     (bit-exact), overlapping the dot's ds_reads.
//   - per-lane weight traffic unchanged vs r3 (one 64-float row/step).
// r3..r15 established weight delivery is NOT the marginal cost; the serial
// chain is. This cuts the chain ~1280 -> ~500 cy/step.
// Blocks [64,192): expert-expert MMD term (r13-identical).
__global__ __launch_bounds__(256) void gen_and_ee(
    const float* __restrict__ upool,   // [B,S]
    const float* __restrict__ texp,    // [B,S]
    const float* __restrict__ Wih,     // [256]
    const float* __restrict__ Whh,     // [256,64]
    const float* __restrict__ bih,     // [256]
    const float* __restrict__ bhh,     // [256]
    const float* __restrict__ Vw,      // [64]
    const float* __restrict__ Vb,      // [1]
    float* __restrict__ tl,            // [NPTS] workspace
    float* __restrict__ out)           // [1] loss accumulator
{
    // [0,4096)      qbuf float2[2048] (EE branch)
    // [4096,4160)   hx_s[64]  (shared state, published once per step)
    // [4160,4288)   lu_s[128]
    __shared__ __align__(16) float smem[4288];

    const int bid = blockIdx.x;
    const int tid = threadIdx.x;

    if (bid < BATCH) {
        const int l   = tid & 63;            // lane
        const int wv  = tid >> 6;            // wave 0..3
        const int u   = (wv << 4) + (l >> 2);// hidden unit 0..63
        const int g   = l & 3;               // gate 0=i 1=f 2=g 3=o
        const int row = (g << 6) + u;        // gate row 0..255

        float* hx_s = smem + 4096;
        float* lu_s = smem + 4160;

        // W_hh row (r3-style preload; compiler may sink -- proven fine)
        v2f w2[32];
        const float4* wrow = (const float4*)(Whh + row * 64);
        #pragma unroll
        for (int k = 0; k < 16; ++k) {
            float4 v = wrow[k];
            w2[2 * k]     = (v2f){v.x, v.y};
            w2[2 * k + 1] = (v2f){v.z, v.w};
        }
        const float bias = bih[row] + bhh[row];
        const float wih  = Wih[row];
        const float vw   = Vw[l];            // sigma: lane l multiplies hx_s[l]
        const float vb   = Vb[0];

        if (tid < SEQ) lu_s[tid] = -flog2(upool[bid * SEQ + tid]) * LN2;
        if (tid < 64) hx_s[tid] = 0.0f;
        float cx = 0.0f;
        barrier_lds_only();

        // step 0: hx = 0 -> sigma = elu(Vb)+1 (uniform)
        float sg0 = (vb > 0.0f) ? (vb + 1.0f) : fexp2(vb * L2E);
        float cum = lu_s[0] * frcp(sg0);
        float keep = (tid == 0) ? cum : 0.0f;   // thread t keeps cum of step t

        #pragma unroll 1
        for (int s = 0; s < SEQ - 1; ++s) {
            // sigma/cum update for THIS step (s>0; s=0's cum set pre-loop).
            // Same lane->hx mapping and DPP association as r3 -> bit-exact.
            if (s > 0) {
                float tot = wave_sum_dpp(hx_s[l] * vw);
                float xx  = tot + vb;
                float sg  = (xx > 0.0f) ? (xx + 1.0f) : fexp2(xx * L2E);
                cum += lu_s[s] * frcp(sg);
                keep = (tid == s) ? cum : keep;
            }

            // gate-row dot hx (broadcast b128 reads; r3-identical pairing)
            const float4* h4 = (const float4*)hx_s;
            v2f a0 = {0.f, 0.f}, a1 = {0.f, 0.f}, a2 = {0.f, 0.f}, a3 = {0.f, 0.f};
            #pragma unroll
            for (int k = 0; k < 16; k += 2) {
                float4 va = h4[k];
                float4 vbq = h4[k + 1];
                a0 = a0 + w2[2 * k]     * (v2f){va.x, va.y};
                a1 = a1 + w2[2 * k + 1] * (v2f){va.z, va.w};
                a2 = a2 + w2[2 * k + 2] * (v2f){vbq.x, vbq.y};
                a3 = a3 + w2[2 * k + 3] * (v2f){vbq.z, vbq.w};
            }
            v2f aa = (a0 + a1) + (a2 + a3);
            float gin = (aa.x + aa.y) + bias + cum * wih;
            // compute both, select (no divergence); selected value bit-exact
            float sig = fsigmoid(gin);
            float tnh = ftanh(gin);
            float a = (g == 2) ? tnh : sig;

            // quad exchange: all 4 gates of unit u into every lane of the quad
            float ig = dpp_mov<0x00>(a);   // quad_perm(0,0,0,0)
            float fg = dpp_mov<0x55>(a);   // quad_perm(1,1,1,1)
            float gg = dpp_mov<0xAA>(a);   // quad_perm(2,2,2,2)
            float og = dpp_mov<0xFF>(a);   // quad_perm(3,3,3,3)

            // cell update, redundant across the quad (bit-identical)
            cx = fg * cx + ig * gg;
            float hx = og * ftanh(cx);
            if (g == 0) hx_s[u] = hx;      // 16 consecutive floats/wave: no conflict
            barrier_lds_only();            // the ONLY barrier per step
        }
        // final sigma/cum for step SEQ-1
        {
            float tot = wave_sum_dpp(hx_s[l] * vw);
            float xx  = tot + vb;
            float sg  = (xx > 0.0f) ? (xx + 1.0f) : fexp2(xx * L2E);
            cum += lu_s[SEQ - 1] * frcp(sg);
            keep = (tid == SEQ - 1) ? cum : keep;
        }
        if (tid < SEQ) tl[bid * SEQ + tid] = keep;
    } else {
        // ---------------- expert-expert MMD term (r13-identical) ----------------
        const int eb = bid - BATCH;      // 0..127
        const int pc = eb & 31;          // p-chunk (256 points)
        const int qs = eb >> 5;          // q-split (2048 points)

        float2* qbuf = (float2*)smem;    // [2048]

        const int p = pc * 256 + tid;
        const float tp = texp[p];
        const float mp = (tp < TMAXV && tp > 0.0f) ? 1.0f : 0.0f;

        const int q0 = qs * 2048;
        for (int i = tid; i < 2048; i += 256) {
            float tq = texp[q0 + i];
            float mq = (tq < TMAXV && tq > 0.0f) ? 1.0f : 0.0f;
            qbuf[i] = make_float2(tq, mq);
        }
        __syncthreads();

        float acc = 0.0f;
        #pragma unroll 4
        for (int i = 0; i < 2048; ++i) {
            float2 qq = qbuf[i];
            float d = tp - qq.x;
            acc = fmaf(qq.y, fexp2(d * d * (-L2E)), acc);
        }
        acc *= mp;
        acc = wave_sum_shfl(acc);
        if ((tid & 63) == 0) atomicAdd(out, acc);
    }
}

// ll + le terms. Grid (32, 16): 32 p-chunks of 256 x 16 q-splits of 512.
__global__ __launch_bounds__(256) void ll_le(
    const float* __restrict__ texp,
    const float* __restrict__ tl,
    float* __restrict__ out)
{
    __shared__ __align__(16) float4 qbuf[512];
    __shared__ float red[4];

    const int pc = blockIdx.x;
    const int qs = blockIdx.y;
    const int tid = threadIdx.x;

    const int p = pc * 256 + tid;
    const float tlp = tl[p];
    const float mlp = (tlp < TMAXV && tlp > 0.0f) ? 1.0f : 0.0f;

    const int q0 = qs * 512;
    for (int i = tid; i < 512; i += 256) {
        float tq = tl[q0 + i];
        float mq = (tq < TMAXV && tq > 0.0f) ? 1.0f : 0.0f;
        float te = texp[q0 + i];
        float me = (te < TMAXV && te > 0.0f) ? 1.0f : 0.0f;
        qbuf[i] = make_float4(tq, mq, te, me);
    }
    __syncthreads();

    float val = 0.0f;
    // learner times are cumsum of Exp(1) increments: most p-points exceed T_MAX;
    // fully-masked waves skip the whole q-loop (wave-uniform branch).
    if (__ballot(mlp != 0.0f) != 0ULL) {
        float a_ll = 0.0f, a_le = 0.0f;
        #pragma unroll 4
        for (int i = 0; i < 512; ++i) {
            float4 q = qbuf[i];
            float d1 = tlp - q.x;
            a_ll = fmaf(q.y, fexp2(d1 * d1 * (-L2E)), a_ll);
            float d2 = tlp - q.z;
            a_le = fmaf(q.w, fexp2(d2 * d2 * (-L2E)), a_le);
        }
        val = mlp * (a_ll - 2.0f * a_le);
    }

    val = wave_sum_shfl(val);
    if ((tid & 63) == 0) red[tid >> 6] = val;
    __syncthreads();
    if (tid == 0) atomicAdd(out, red[0] + red[1] + red[2] + red[3]);
}

extern "C" void kernel_launch(void* const* d_in, const int* in_sizes, int n_in,
                              void* d_out, int out_size, void* d_ws, size_t ws_size,
                              hipStream_t stream) {
    const float* upool = (const float*)d_in[0];
    const float* texp  = (const float*)d_in[1];
    const float* Wih   = (const float*)d_in[2];
    const float* Whh   = (const float*)d_in[3];
    const float* bih   = (const float*)d_in[4];
    const float* bhh   = (const float*)d_in[5];
    const float* Vw    = (const float*)d_in[6];
    const float* Vb    = (const float*)d_in[7];
    float* out = (float*)d_out;
    float* tl  = (float*)d_ws;   // 8192 floats = 32 KB

    hipMemsetAsync(out, 0, sizeof(float), stream);
    hipLaunchKernelGGL(gen_and_ee, dim3(BATCH + 128), dim3(256), 0, stream,
                       upool, texp, Wih, Whh, bih, bhh, Vw, Vb, tl, out);
    hipLaunchKernelGGL(ll_le, dim3(32, 16), dim3(256), 0, stream, texp, tl, out);
}